// Round 7
// baseline (239.775 us; speedup 1.0000x reference)
//
#include <hip/hip_runtime.h>
#include <stdint.h>

// Problem dims (fixed by reference)
#define Bb  4
#define Ss  1024
#define Tt  1024
#define Cc  1024
#define Hh  16
#define HDd 64
#define Kk  1024   // inner dim for all projections (QIN=CTX=C=1024)

typedef __bf16 bf16;
typedef __bf16 bf16x8 __attribute__((ext_vector_type(8)));
typedef float  f32x4  __attribute__((ext_vector_type(4)));
typedef __attribute__((address_space(1))) uint32_t gu32;
typedef __attribute__((address_space(3))) uint32_t lu32;

// async global->LDS, 16B per lane; LDS dest = wave-uniform base + lane*16
__device__ __forceinline__ void load_lds16(const bf16* g, bf16* l) {
    __builtin_amdgcn_global_load_lds((gu32*)g, (lu32*)l, 16, 0, 0);
}

// ---------------------------------------------------------------------------
// fp32 -> bf16 convert, 8 elems/thread; 7 tensors via blockIdx.y
// ---------------------------------------------------------------------------
__global__ void cvt8(const float* __restrict__ s0, const float* __restrict__ s1,
                     const float* __restrict__ s2, const float* __restrict__ s3,
                     const float* __restrict__ s4, const float* __restrict__ s5,
                     const float* __restrict__ s6,
                     bf16* __restrict__ d0, bf16* __restrict__ d1,
                     bf16* __restrict__ d2, bf16* __restrict__ d3,
                     bf16* __restrict__ d4, bf16* __restrict__ d5,
                     bf16* __restrict__ d6)
{
    const float* s; bf16* d; int n;
    switch (blockIdx.y) {
        case 0: s = s0; d = d0; n = Bb * Ss * Kk; break;
        case 1: s = s1; d = d1; n = Bb * Ss * Kk; break;
        case 2: s = s2; d = d2; n = Bb * Ss * Kk; break;
        case 3: s = s3; d = d3; n = Cc * Kk; break;
        case 4: s = s4; d = d4; n = Cc * Kk; break;
        case 5: s = s5; d = d5; n = Cc * Kk; break;
        default: s = s6; d = d6; n = Cc * Kk; break;
    }
    const int i = (blockIdx.x * blockDim.x + threadIdx.x) * 8;
    if (i >= n) return;
    const float4 a = *(const float4*)(s + i);
    const float4 c = *(const float4*)(s + i + 4);
    bf16x8 o;
    o[0] = (bf16)a.x; o[1] = (bf16)a.y; o[2] = (bf16)a.z; o[3] = (bf16)a.w;
    o[4] = (bf16)c.x; o[5] = (bf16)c.y; o[6] = (bf16)c.z; o[7] = (bf16)c.w;
    *(bf16x8*)(d + i) = o;
}

// ---------------------------------------------------------------------------
// NT-GEMM mainloop, 128x64 C-tile, BK=64, XOR-swizzled LDS (chunk ^ row&7).
// 4 waves 2x2, each 64x32 = 4x2 MFMA tiles x 2 k-halves = 16 MFMA/k-step.
// ---------------------------------------------------------------------------
__device__ __forceinline__ void mainloop_128x64(
    const bf16* __restrict__ Ab, const bf16* __restrict__ Wb,
    bf16* As, bf16* Bs, f32x4 acc[4][2])
{
    const int tid  = threadIdx.x;
    const int wid  = tid >> 6;
    const int lane = tid & 63;
    const int l16  = lane & 15;
    const int quad = lane >> 4;
    const int wm   = wid >> 1;
    const int wn   = wid & 1;
    const int r8   = lane >> 3;              // row within 8-row staging chunk
    const int ssw  = ((lane & 7) ^ r8) * 8;  // swizzled k-chunk (elems)

    for (int k0 = 0; k0 < Kk; k0 += 64) {
#pragma unroll
        for (int p = 0; p < 4; p++) {        // A: 128 rows
            const int rb = wid * 32 + p * 8;
            load_lds16(Ab + (size_t)(rb + r8) * Kk + k0 + ssw, As + rb * 64);
        }
#pragma unroll
        for (int p = 0; p < 2; p++) {        // B: 64 rows
            const int rb = wid * 16 + p * 8;
            load_lds16(Wb + (size_t)(rb + r8) * Kk + k0 + ssw, Bs + rb * 64);
        }
        __syncthreads();   // drains vmcnt(0) -> staging complete
#pragma unroll
        for (int kh = 0; kh < 2; kh++) {
            bf16x8 af[4], bw[2];
#pragma unroll
            for (int i = 0; i < 4; i++)
                af[i] = *(const bf16x8*)(As + (wm * 64 + i * 16 + l16) * 64 +
                                         (((kh * 4 + quad) ^ (l16 & 7)) * 8));
#pragma unroll
            for (int j = 0; j < 2; j++)
                bw[j] = *(const bf16x8*)(Bs + (wn * 32 + j * 16 + l16) * 64 +
                                         (((kh * 4 + quad) ^ (l16 & 7)) * 8));
#pragma unroll
            for (int i = 0; i < 4; i++)
#pragma unroll
                for (int j = 0; j < 2; j++)
                    acc[i][j] = __builtin_amdgcn_mfma_f32_16x16x32_bf16(af[i], bw[j], acc[i][j], 0, 0, 0);
        }
        __syncthreads();   // protect LDS before next stage
    }
}

// 64x64 C-tile variant (for gemm_out): 4 waves 2x2, each 32x32.
__device__ __forceinline__ void mainloop_64x64(
    const bf16* __restrict__ Ab, const bf16* __restrict__ Wb,
    bf16* As, bf16* Bs, f32x4 acc[2][2])
{
    const int tid  = threadIdx.x;
    const int wid  = tid >> 6;
    const int lane = tid & 63;
    const int l16  = lane & 15;
    const int quad = lane >> 4;
    const int wm   = wid >> 1;
    const int wn   = wid & 1;
    const int r8   = lane >> 3;
    const int ssw  = ((lane & 7) ^ r8) * 8;

    for (int k0 = 0; k0 < Kk; k0 += 64) {
#pragma unroll
        for (int p = 0; p < 2; p++) {        // A: 64 rows
            const int rb = wid * 16 + p * 8;
            load_lds16(Ab + (size_t)(rb + r8) * Kk + k0 + ssw, As + rb * 64);
        }
#pragma unroll
        for (int p = 0; p < 2; p++) {        // B: 64 rows
            const int rb = wid * 16 + p * 8;
            load_lds16(Wb + (size_t)(rb + r8) * Kk + k0 + ssw, Bs + rb * 64);
        }
        __syncthreads();
#pragma unroll
        for (int kh = 0; kh < 2; kh++) {
            bf16x8 af[2], bw[2];
#pragma unroll
            for (int i = 0; i < 2; i++)
                af[i] = *(const bf16x8*)(As + (wm * 32 + i * 16 + l16) * 64 +
                                         (((kh * 4 + quad) ^ (l16 & 7)) * 8));
#pragma unroll
            for (int j = 0; j < 2; j++)
                bw[j] = *(const bf16x8*)(Bs + (wn * 32 + j * 16 + l16) * 64 +
                                         (((kh * 4 + quad) ^ (l16 & 7)) * 8));
#pragma unroll
            for (int i = 0; i < 2; i++)
#pragma unroll
                for (int j = 0; j < 2; j++)
                    acc[i][j] = __builtin_amdgcn_mfma_f32_16x16x32_bf16(af[i], bw[j], acc[i][j], 0, 0, 0);
        }
        __syncthreads();
    }
}

// QKV projections: z selects {Q,K,V}. Q,K -> (B,H,S,HD); V -> (B,H,HD,T)
// Tile 128x64, grid (32, 16, 3). XCD swizzle: blocks sharing a W-tile (same
// yy) land on one XCD so W stays L2-resident.
__global__ __launch_bounds__(256)
void gemm_qkv(const bf16* __restrict__ Aq, const bf16* __restrict__ Ak, const bf16* __restrict__ Av,
              const bf16* __restrict__ Wq, const bf16* __restrict__ Wk, const bf16* __restrict__ Wv,
              const float* __restrict__ bq, const float* __restrict__ bk, const float* __restrict__ bv,
              bf16* __restrict__ Oq, bf16* __restrict__ Ok, bf16* __restrict__ Ov)
{
    __shared__ __align__(16) bf16 As[128 * 64];   // 16 KB
    __shared__ __align__(16) bf16 Bs[64 * 64];    // 8 KB
    const int z = blockIdx.z;
    const bf16*  A    = (z == 0) ? Aq : (z == 1) ? Ak : Av;
    const bf16*  W    = (z == 0) ? Wq : (z == 1) ? Wk : Wv;
    const float* bias = (z == 0) ? bq : (z == 1) ? bk : bv;
    bf16*        O    = (z == 0) ? Oq : (z == 1) ? Ok : Ov;

    // XCD-locality remap: f%8 = XCD; give each XCD 2 consecutive yy-tiles.
    const int f   = blockIdx.x + 32 * blockIdx.y;
    const int xcd = f & 7, idx = f >> 3;          // idx in [0,64)
    const int yy  = xcd * 2 + (idx >> 5);         // N-tile [0,16)
    const int xx  = idx & 31;                     // M-tile [0,32)

    f32x4 acc[4][2];
    const f32x4 z4 = {0.f, 0.f, 0.f, 0.f};
#pragma unroll
    for (int i = 0; i < 4; i++)
#pragma unroll
        for (int j = 0; j < 2; j++) acc[i][j] = z4;

    mainloop_128x64(A + (size_t)xx * 128 * Kk,
                    W + (size_t)yy * 64 * Kk, As, Bs, acc);

    const int tid = threadIdx.x;
    const int wid = tid >> 6, lane = tid & 63;
    const int l16 = lane & 15, quad = lane >> 4;
    const int wm = wid >> 1, wn = wid & 1;
    const int row0 = xx * 128 + wm * 64;
    const int col0 = yy * 64 + wn * 32;
#pragma unroll
    for (int j = 0; j < 2; j++) {
        const int col = col0 + j * 16 + l16;     // c = h*64 + d
        const float bj = bias[col];
        const int h = col >> 6, d = col & 63;
#pragma unroll
        for (int i = 0; i < 4; i++) {
#pragma unroll
            for (int r = 0; r < 4; r++) {
                const int row = row0 + i * 16 + quad * 4 + r;  // row = b*S + s
                const int b = row >> 10, s = row & 1023;
                const bf16 val = (bf16)(acc[i][j][r] + bj);
                if (z == 2) {
                    Ov[((size_t)((b * Hh + h) * HDd + d)) * Tt + s] = val;  // V^T
                } else {
                    O[((size_t)(b * Hh + h) * Ss + s) * HDd + d] = val;
                }
            }
        }
    }
}

// Output projection: 64x64 tile, flat grid 1024, XCD swizzle (2 yy per XCD).
// fp32 out, + bias, * rowmask (mask[b,s,0])
__global__ __launch_bounds__(256)
void gemm_out(const bf16* __restrict__ A, const bf16* __restrict__ W,
              const float* __restrict__ bias, const int* __restrict__ mask,
              float* __restrict__ out)
{
    __shared__ __align__(16) bf16 As[64 * 64];    // 8 KB
    __shared__ __align__(16) bf16 Bs[64 * 64];    // 8 KB
    const int g   = blockIdx.x;
    const int xcd = g & 7, idx = g >> 3;          // idx in [0,128)
    const int yy  = xcd * 2 + (idx >> 6);         // N-tile [0,16)
    const int xx  = idx & 63;                     // M-tile [0,64)

    f32x4 acc[2][2];
    const f32x4 z4 = {0.f, 0.f, 0.f, 0.f};
#pragma unroll
    for (int i = 0; i < 2; i++)
#pragma unroll
        for (int j = 0; j < 2; j++) acc[i][j] = z4;

    mainloop_64x64(A + (size_t)xx * 64 * Kk,
                   W + (size_t)yy * 64 * Kk, As, Bs, acc);

    const int tid = threadIdx.x;
    const int wid = tid >> 6, lane = tid & 63;
    const int l16 = lane & 15, quad = lane >> 4;
    const int wm = wid >> 1, wn = wid & 1;
    const int row0 = xx * 64 + wm * 32;
    const int col0 = yy * 64 + wn * 32;
#pragma unroll
    for (int j = 0; j < 2; j++) {
        const int col = col0 + j * 16 + l16;
        const float bj = bias[col];
#pragma unroll
        for (int i = 0; i < 2; i++) {
#pragma unroll
            for (int r = 0; r < 4; r++) {
                const int row = row0 + i * 16 + quad * 4 + r;
                const float mval = (mask[(size_t)row * Tt] != 0) ? 1.f : 0.f;
                out[(size_t)row * Cc + col] = (acc[i][j][r] + bj) * mval;
            }
        }
    }
}

// ---------------------------------------------------------------------------
// Flash attention v2 + XCD swizzle: flat grid 1024; all 16 q-blocks of one
// (b,h) land on the same XCD so K/V (256 KB per bh) stays L2-resident and the
// per-tile vmcnt drain is an L2-hit (~200cyc) instead of HBM (~900cyc).
// ---------------------------------------------------------------------------
__global__ __launch_bounds__(256)
void attn(const bf16* __restrict__ Q, const bf16* __restrict__ Kp, const bf16* __restrict__ Vt,
          const int* __restrict__ mask, bf16* __restrict__ X)
{
    __shared__ __align__(16) bf16 Ks[64 * 64];    // [t_local][d]  (swizzled)
    __shared__ __align__(16) bf16 Vs[64 * 64];    // [d][t_local]  (swizzled)
    __shared__ __align__(16) bf16 Ps[4][16 * 72]; // per-wave P, row stride 72
    const int g   = blockIdx.x;
    const int xcd = g & 7, idx = g >> 3;          // idx in [0,128)
    const int bh  = xcd * 8 + (idx >> 4);         // [0,64): 8 bh per XCD
    const int qblk = idx & 15;                    // q-block [0,16)
    const int b = bh >> 4, h = bh & 15;
    const int tid = threadIdx.x, wid = tid >> 6, lane = tid & 63;
    const int l16 = lane & 15, quad = lane >> 4;
    const bf16* Qbh = Q  + (size_t)bh * Ss * HDd;
    const bf16* Kbh = Kp + (size_t)bh * Tt * HDd;
    const bf16* Vbh = Vt + (size_t)bh * HDd * Tt;
    const int*  mb  = mask + (size_t)b * Ss * Tt;  // mb[t] = mask[b,0,t]
    const int q0 = qblk * 64 + wid * 16;
    bf16* Psw = &Ps[wid][0];

    // Q fragments (A-layout): rows q0+l16, k halves [0,32) and [32,64)
    const bf16x8 qf0 = *(const bf16x8*)(Qbh + (size_t)(q0 + l16) * HDd + quad * 8);
    const bf16x8 qf1 = *(const bf16x8*)(Qbh + (size_t)(q0 + l16) * HDd + 32 + quad * 8);

    float ls[4];
    f32x4 o[4];
    const f32x4 z4 = {0.f, 0.f, 0.f, 0.f};
#pragma unroll
    for (int r = 0; r < 4; r++) ls[r] = 0.f;
#pragma unroll
    for (int dblk = 0; dblk < 4; dblk++) o[dblk] = z4;

    // staging lane decomposition: 8 lanes per 64-elem (128B) row
    const int srow = lane >> 3;          // 0..7: row within an 8-row chunk
    const int schk = lane & 7;           // 0..7: 16B chunk within the row
    const int sswz = (schk ^ srow) * 8;  // swizzled source element offset

    for (int kt = 0; kt < Tt; kt += 64) {
        // stage K-tile (8 calls of 8 rows) and V^T-tile, 2+2 calls per wave
#pragma unroll
        for (int p = 0; p < 2; p++) {
            const int c8 = wid * 2 + p;                    // 0..7
            load_lds16(Kbh + (size_t)(kt + c8 * 8 + srow) * HDd + sswz,
                       Ks + c8 * 512);
            load_lds16(Vbh + (size_t)(c8 * 8 + srow) * Tt + kt + sswz,
                       Vs + c8 * 512);
        }
        __syncthreads();   // vmcnt(0) drain: staging visible

        // QK^T: 4 n-blocks of 16 keys, 2 k-halves of 32 channels
        f32x4 sc[4];
#pragma unroll
        for (int nb = 0; nb < 4; nb++) sc[nb] = z4;
#pragma unroll
        for (int nb = 0; nb < 4; nb++) {
            const bf16* krow = Ks + (nb * 16 + l16) * 64;
            const bf16x8 kf0 = *(const bf16x8*)(krow + ((quad     ^ (l16 & 7)) * 8));
            const bf16x8 kf1 = *(const bf16x8*)(krow + (((4 + quad) ^ (l16 & 7)) * 8));
            sc[nb] = __builtin_amdgcn_mfma_f32_16x16x32_bf16(qf0, kf0, sc[nb], 0, 0, 0);
            sc[nb] = __builtin_amdgcn_mfma_f32_16x16x32_bf16(qf1, kf1, sc[nb], 0, 0, 0);
        }

        // softmax numerator (no max subtraction) + P store (C->A layout)
#pragma unroll
        for (int nb = 0; nb < 4; nb++) {
            const float madd = mb[kt + nb * 16 + l16] ? 0.f : -1e30f;
#pragma unroll
            for (int r = 0; r < 4; r++) {
                const float p = __expf(sc[nb][r] * 0.125f + madd);
                ls[r] += p;
                Psw[(quad * 4 + r) * 72 + nb * 16 + l16] = (bf16)p;
            }
        }

        // O += P @ V : A = P (rows q), B = V^T (rows d), k = t in 2 halves
#pragma unroll
        for (int kh = 0; kh < 2; kh++) {
            const bf16x8 pf = *(const bf16x8*)(Psw + l16 * 72 + kh * 32 + quad * 8);
#pragma unroll
            for (int dblk = 0; dblk < 4; dblk++) {
                const bf16x8 vf = *(const bf16x8*)(Vs + (dblk * 16 + l16) * 64 +
                                                   (((kh * 4 + quad) ^ (l16 & 7)) * 8));
                o[dblk] = __builtin_amdgcn_mfma_f32_16x16x32_bf16(pf, vf, o[dblk], 0, 0, 0);
            }
        }
        __syncthreads();   // all reads done before next stage overwrites
    }

    // row sums: reduce ls across the 16 l16 lanes
#pragma unroll
    for (int off = 1; off <= 8; off <<= 1)
#pragma unroll
        for (int r = 0; r < 4; r++)
            ls[r] += __shfl_xor(ls[r], off, 64);
    float inv[4];
#pragma unroll
    for (int r = 0; r < 4; r++) inv[r] = 1.f / ls[r];

#pragma unroll
    for (int dblk = 0; dblk < 4; dblk++) {
#pragma unroll
        for (int r = 0; r < 4; r++) {
            const int srow_q = q0 + quad * 4 + r;
            const int d = dblk * 16 + l16;
            X[(size_t)(b * Ss + srow_q) * Cc + h * HDd + d] = (bf16)(o[dblk][r] * inv[r]);
        }
    }
}

// ---------------------------------------------------------------------------
extern "C" void kernel_launch(void* const* d_in, const int* in_sizes, int n_in,
                              void* d_out, int out_size, void* d_ws, size_t ws_size,
                              hipStream_t stream)
{
    const float* query = (const float*)d_in[0];
    const float* key   = (const float*)d_in[1];
    const float* value = (const float*)d_in[2];
    const int*   mask  = (const int*)d_in[3];
    const float* Wq = (const float*)d_in[4];
    const float* bq = (const float*)d_in[5];
    const float* Wk = (const float*)d_in[6];
    const float* bk = (const float*)d_in[7];
    const float* Wv = (const float*)d_in[8];
    const float* bv = (const float*)d_in[9];
    const float* Wo = (const float*)d_in[10];
    const float* bo = (const float*)d_in[11];
    float* out = (float*)d_out;

    char* ws = (char*)d_ws;
    const size_t MB = 1024 * 1024;
    bf16* qb  = (bf16*)(ws + 0 * MB);
    bf16* kb  = (bf16*)(ws + 8 * MB);
    bf16* vb  = (bf16*)(ws + 16 * MB);
    bf16* wqb = (bf16*)(ws + 24 * MB);
    bf16* wkb = (bf16*)(ws + 26 * MB);
    bf16* wvb = (bf16*)(ws + 28 * MB);
    bf16* wob = (bf16*)(ws + 30 * MB);
    bf16* Qp  = (bf16*)(ws + 32 * MB);   // (B,H,S,HD) bf16
    bf16* Kpp = (bf16*)(ws + 40 * MB);   // (B,H,T,HD) bf16
    bf16* Vtp = (bf16*)(ws + 48 * MB);   // (B,H,HD,T) bf16
    bf16* Xb  = (bf16*)(ws + 56 * MB);   // attn out (B*S, C) bf16

    cvt8<<<dim3(2048, 7), 256, 0, stream>>>(query, key, value, Wq, Wk, Wv, Wo,
                                            qb, kb, vb, wqb, wkb, wvb, wob);
    gemm_qkv<<<dim3(32, 16, 3), 256, 0, stream>>>(qb, kb, vb, wqb, wkb, wvb,
                                                  bq, bk, bv, Qp, Kpp, Vtp);
    attn<<<dim3(1024), 256, 0, stream>>>(Qp, Kpp, Vtp, mask, Xb);
    gemm_out<<<dim3(1024), 256, 0, stream>>>(Xb, wob, bo, mask, out);
}

// Round 8
// 228.046 us; speedup vs baseline: 1.0514x; 1.0514x over previous
//
#include <hip/hip_runtime.h>
#include <stdint.h>

// Problem dims (fixed by reference)
#define Bb  4
#define Ss  1024
#define Tt  1024
#define Cc  1024
#define Hh  16
#define HDd 64
#define Kk  1024   // inner dim for all projections (QIN=CTX=C=1024)

typedef __bf16 bf16;
typedef __bf16 bf16x8 __attribute__((ext_vector_type(8)));
typedef float  f32x4  __attribute__((ext_vector_type(4)));
typedef __attribute__((address_space(1))) uint32_t gu32;
typedef __attribute__((address_space(3))) uint32_t lu32;

// async global->LDS, 16B per lane; LDS dest = wave-uniform base + lane*16
__device__ __forceinline__ void load_lds16(const bf16* g, bf16* l) {
    __builtin_amdgcn_global_load_lds((gu32*)g, (lu32*)l, 16, 0, 0);
}

// ---------------------------------------------------------------------------
// fp32 -> bf16 convert, 8 elems/thread; 7 tensors via blockIdx.y
// ---------------------------------------------------------------------------
__global__ void cvt8(const float* __restrict__ s0, const float* __restrict__ s1,
                     const float* __restrict__ s2, const float* __restrict__ s3,
                     const float* __restrict__ s4, const float* __restrict__ s5,
                     const float* __restrict__ s6,
                     bf16* __restrict__ d0, bf16* __restrict__ d1,
                     bf16* __restrict__ d2, bf16* __restrict__ d3,
                     bf16* __restrict__ d4, bf16* __restrict__ d5,
                     bf16* __restrict__ d6)
{
    const float* s; bf16* d; int n;
    switch (blockIdx.y) {
        case 0: s = s0; d = d0; n = Bb * Ss * Kk; break;
        case 1: s = s1; d = d1; n = Bb * Ss * Kk; break;
        case 2: s = s2; d = d2; n = Bb * Ss * Kk; break;
        case 3: s = s3; d = d3; n = Cc * Kk; break;
        case 4: s = s4; d = d4; n = Cc * Kk; break;
        case 5: s = s5; d = d5; n = Cc * Kk; break;
        default: s = s6; d = d6; n = Cc * Kk; break;
    }
    const int i = (blockIdx.x * blockDim.x + threadIdx.x) * 8;
    if (i >= n) return;
    const float4 a = *(const float4*)(s + i);
    const float4 c = *(const float4*)(s + i + 4);
    bf16x8 o;
    o[0] = (bf16)a.x; o[1] = (bf16)a.y; o[2] = (bf16)a.z; o[3] = (bf16)a.w;
    o[4] = (bf16)c.x; o[5] = (bf16)c.y; o[6] = (bf16)c.z; o[7] = (bf16)c.w;
    *(bf16x8*)(d + i) = o;
}

// ---------------------------------------------------------------------------
// NT-GEMM mainloop, 128x64 C-tile, BK=64, XOR-swizzled LDS (chunk ^ row&7).
// 4 waves 2x2, each 64x32 = 4x2 MFMA tiles x 2 k-halves = 16 MFMA/k-step.
// NOTE: natural blockIdx mapping kept deliberately — default round-robin
// (f%8 = XCD) gives each XCD a FIXED set of A-tiles (L2-resident) x all
// W-tiles (2 MB, resident). Round-7's yy-grouping remap thrashed A
// (FETCH 37 -> 104 MB). Do not "optimize" the grid mapping here again.
// ---------------------------------------------------------------------------
__device__ __forceinline__ void mainloop_128x64(
    const bf16* __restrict__ Ab, const bf16* __restrict__ Wb,
    bf16* As, bf16* Bs, f32x4 acc[4][2])
{
    const int tid  = threadIdx.x;
    const int wid  = tid >> 6;
    const int lane = tid & 63;
    const int l16  = lane & 15;
    const int quad = lane >> 4;
    const int wm   = wid >> 1;
    const int wn   = wid & 1;
    const int r8   = lane >> 3;              // row within 8-row staging chunk
    const int ssw  = ((lane & 7) ^ r8) * 8;  // swizzled k-chunk (elems)

    for (int k0 = 0; k0 < Kk; k0 += 64) {
#pragma unroll
        for (int p = 0; p < 4; p++) {        // A: 128 rows
            const int rb = wid * 32 + p * 8;
            load_lds16(Ab + (size_t)(rb + r8) * Kk + k0 + ssw, As + rb * 64);
        }
#pragma unroll
        for (int p = 0; p < 2; p++) {        // B: 64 rows
            const int rb = wid * 16 + p * 8;
            load_lds16(Wb + (size_t)(rb + r8) * Kk + k0 + ssw, Bs + rb * 64);
        }
        __syncthreads();   // drains vmcnt(0) -> staging complete
#pragma unroll
        for (int kh = 0; kh < 2; kh++) {
            bf16x8 af[4], bw[2];
#pragma unroll
            for (int i = 0; i < 4; i++)
                af[i] = *(const bf16x8*)(As + (wm * 64 + i * 16 + l16) * 64 +
                                         (((kh * 4 + quad) ^ (l16 & 7)) * 8));
#pragma unroll
            for (int j = 0; j < 2; j++)
                bw[j] = *(const bf16x8*)(Bs + (wn * 32 + j * 16 + l16) * 64 +
                                         (((kh * 4 + quad) ^ (l16 & 7)) * 8));
#pragma unroll
            for (int i = 0; i < 4; i++)
#pragma unroll
                for (int j = 0; j < 2; j++)
                    acc[i][j] = __builtin_amdgcn_mfma_f32_16x16x32_bf16(af[i], bw[j], acc[i][j], 0, 0, 0);
        }
        __syncthreads();   // protect LDS before next stage
    }
}

// 64x64 C-tile variant (for gemm_out): 4 waves 2x2, each 32x32.
__device__ __forceinline__ void mainloop_64x64(
    const bf16* __restrict__ Ab, const bf16* __restrict__ Wb,
    bf16* As, bf16* Bs, f32x4 acc[2][2])
{
    const int tid  = threadIdx.x;
    const int wid  = tid >> 6;
    const int lane = tid & 63;
    const int l16  = lane & 15;
    const int quad = lane >> 4;
    const int wm   = wid >> 1;
    const int wn   = wid & 1;
    const int r8   = lane >> 3;
    const int ssw  = ((lane & 7) ^ r8) * 8;

    for (int k0 = 0; k0 < Kk; k0 += 64) {
#pragma unroll
        for (int p = 0; p < 2; p++) {        // A: 64 rows
            const int rb = wid * 16 + p * 8;
            load_lds16(Ab + (size_t)(rb + r8) * Kk + k0 + ssw, As + rb * 64);
        }
#pragma unroll
        for (int p = 0; p < 2; p++) {        // B: 64 rows
            const int rb = wid * 16 + p * 8;
            load_lds16(Wb + (size_t)(rb + r8) * Kk + k0 + ssw, Bs + rb * 64);
        }
        __syncthreads();
#pragma unroll
        for (int kh = 0; kh < 2; kh++) {
            bf16x8 af[2], bw[2];
#pragma unroll
            for (int i = 0; i < 2; i++)
                af[i] = *(const bf16x8*)(As + (wm * 32 + i * 16 + l16) * 64 +
                                         (((kh * 4 + quad) ^ (l16 & 7)) * 8));
#pragma unroll
            for (int j = 0; j < 2; j++)
                bw[j] = *(const bf16x8*)(Bs + (wn * 32 + j * 16 + l16) * 64 +
                                         (((kh * 4 + quad) ^ (l16 & 7)) * 8));
#pragma unroll
            for (int i = 0; i < 2; i++)
#pragma unroll
                for (int j = 0; j < 2; j++)
                    acc[i][j] = __builtin_amdgcn_mfma_f32_16x16x32_bf16(af[i], bw[j], acc[i][j], 0, 0, 0);
        }
        __syncthreads();
    }
}

// QKV projections: z selects {Q,K,V}. Q,K -> (B,H,S,HD); V -> (B,H,HD,T)
// Tile 128x64, grid (32, 16, 3) = 1536 blocks = 6/CU. Natural mapping.
__global__ __launch_bounds__(256)
void gemm_qkv(const bf16* __restrict__ Aq, const bf16* __restrict__ Ak, const bf16* __restrict__ Av,
              const bf16* __restrict__ Wq, const bf16* __restrict__ Wk, const bf16* __restrict__ Wv,
              const float* __restrict__ bq, const float* __restrict__ bk, const float* __restrict__ bv,
              bf16* __restrict__ Oq, bf16* __restrict__ Ok, bf16* __restrict__ Ov)
{
    __shared__ __align__(16) bf16 As[128 * 64];   // 16 KB
    __shared__ __align__(16) bf16 Bs[64 * 64];    // 8 KB
    const int z = blockIdx.z;
    const bf16*  A    = (z == 0) ? Aq : (z == 1) ? Ak : Av;
    const bf16*  W    = (z == 0) ? Wq : (z == 1) ? Wk : Wv;
    const float* bias = (z == 0) ? bq : (z == 1) ? bk : bv;
    bf16*        O    = (z == 0) ? Oq : (z == 1) ? Ok : Ov;

    f32x4 acc[4][2];
    const f32x4 z4 = {0.f, 0.f, 0.f, 0.f};
#pragma unroll
    for (int i = 0; i < 4; i++)
#pragma unroll
        for (int j = 0; j < 2; j++) acc[i][j] = z4;

    mainloop_128x64(A + (size_t)blockIdx.x * 128 * Kk,
                    W + (size_t)blockIdx.y * 64 * Kk, As, Bs, acc);

    const int tid = threadIdx.x;
    const int wid = tid >> 6, lane = tid & 63;
    const int l16 = lane & 15, quad = lane >> 4;
    const int wm = wid >> 1, wn = wid & 1;
    const int row0 = blockIdx.x * 128 + wm * 64;
    const int col0 = blockIdx.y * 64 + wn * 32;
#pragma unroll
    for (int j = 0; j < 2; j++) {
        const int col = col0 + j * 16 + l16;     // c = h*64 + d
        const float bj = bias[col];
        const int h = col >> 6, d = col & 63;
#pragma unroll
        for (int i = 0; i < 4; i++) {
#pragma unroll
            for (int r = 0; r < 4; r++) {
                const int row = row0 + i * 16 + quad * 4 + r;  // row = b*S + s
                const int b = row >> 10, s = row & 1023;
                const bf16 val = (bf16)(acc[i][j][r] + bj);
                if (z == 2) {
                    Ov[((size_t)((b * Hh + h) * HDd + d)) * Tt + s] = val;  // V^T
                } else {
                    O[((size_t)(b * Hh + h) * Ss + s) * HDd + d] = val;
                }
            }
        }
    }
}

// Output projection: 64x64 tile, grid (64, 16) = 1024 blocks = 4/CU.
// Natural mapping. fp32 out, + bias, * rowmask (mask[b,s,0])
__global__ __launch_bounds__(256)
void gemm_out(const bf16* __restrict__ A, const bf16* __restrict__ W,
              const float* __restrict__ bias, const int* __restrict__ mask,
              float* __restrict__ out)
{
    __shared__ __align__(16) bf16 As[64 * 64];    // 8 KB
    __shared__ __align__(16) bf16 Bs[64 * 64];    // 8 KB
    f32x4 acc[2][2];
    const f32x4 z4 = {0.f, 0.f, 0.f, 0.f};
#pragma unroll
    for (int i = 0; i < 2; i++)
#pragma unroll
        for (int j = 0; j < 2; j++) acc[i][j] = z4;

    mainloop_64x64(A + (size_t)blockIdx.x * 64 * Kk,
                   W + (size_t)blockIdx.y * 64 * Kk, As, Bs, acc);

    const int tid = threadIdx.x;
    const int wid = tid >> 6, lane = tid & 63;
    const int l16 = lane & 15, quad = lane >> 4;
    const int wm = wid >> 1, wn = wid & 1;
    const int row0 = blockIdx.x * 64 + wm * 32;
    const int col0 = blockIdx.y * 64 + wn * 32;
#pragma unroll
    for (int j = 0; j < 2; j++) {
        const int col = col0 + j * 16 + l16;
        const float bj = bias[col];
#pragma unroll
        for (int i = 0; i < 2; i++) {
#pragma unroll
            for (int r = 0; r < 4; r++) {
                const int row = row0 + i * 16 + quad * 4 + r;
                const float mval = (mask[(size_t)row * Tt] != 0) ? 1.f : 0.f;
                out[(size_t)row * Cc + col] = (acc[i][j][r] + bj) * mval;
            }
        }
    }
}

// ---------------------------------------------------------------------------
// Flash attention v2 + XCD swizzle (KEEP): flat grid 1024; all 16 q-blocks of
// one (b,h) land on the same XCD so K/V (256 KB per bh) stays L2-resident and
// the per-tile vmcnt drain is an L2-hit (~200cyc) instead of HBM (~900cyc).
// ---------------------------------------------------------------------------
__global__ __launch_bounds__(256)
void attn(const bf16* __restrict__ Q, const bf16* __restrict__ Kp, const bf16* __restrict__ Vt,
          const int* __restrict__ mask, bf16* __restrict__ X)
{
    __shared__ __align__(16) bf16 Ks[64 * 64];    // [t_local][d]  (swizzled)
    __shared__ __align__(16) bf16 Vs[64 * 64];    // [d][t_local]  (swizzled)
    __shared__ __align__(16) bf16 Ps[4][16 * 72]; // per-wave P, row stride 72
    const int g   = blockIdx.x;
    const int xcd = g & 7, idx = g >> 3;          // idx in [0,128)
    const int bh  = xcd * 8 + (idx >> 4);         // [0,64): 8 bh per XCD
    const int qblk = idx & 15;                    // q-block [0,16)
    const int b = bh >> 4, h = bh & 15;
    const int tid = threadIdx.x, wid = tid >> 6, lane = tid & 63;
    const int l16 = lane & 15, quad = lane >> 4;
    const bf16* Qbh = Q  + (size_t)bh * Ss * HDd;
    const bf16* Kbh = Kp + (size_t)bh * Tt * HDd;
    const bf16* Vbh = Vt + (size_t)bh * HDd * Tt;
    const int*  mb  = mask + (size_t)b * Ss * Tt;  // mb[t] = mask[b,0,t]
    const int q0 = qblk * 64 + wid * 16;
    bf16* Psw = &Ps[wid][0];

    // Q fragments (A-layout): rows q0+l16, k halves [0,32) and [32,64)
    const bf16x8 qf0 = *(const bf16x8*)(Qbh + (size_t)(q0 + l16) * HDd + quad * 8);
    const bf16x8 qf1 = *(const bf16x8*)(Qbh + (size_t)(q0 + l16) * HDd + 32 + quad * 8);

    float ls[4];
    f32x4 o[4];
    const f32x4 z4 = {0.f, 0.f, 0.f, 0.f};
#pragma unroll
    for (int r = 0; r < 4; r++) ls[r] = 0.f;
#pragma unroll
    for (int dblk = 0; dblk < 4; dblk++) o[dblk] = z4;

    // staging lane decomposition: 8 lanes per 64-elem (128B) row
    const int srow = lane >> 3;          // 0..7: row within an 8-row chunk
    const int schk = lane & 7;           // 0..7: 16B chunk within the row
    const int sswz = (schk ^ srow) * 8;  // swizzled source element offset

    for (int kt = 0; kt < Tt; kt += 64) {
        // stage K-tile (8 calls of 8 rows) and V^T-tile, 2+2 calls per wave
#pragma unroll
        for (int p = 0; p < 2; p++) {
            const int c8 = wid * 2 + p;                    // 0..7
            load_lds16(Kbh + (size_t)(kt + c8 * 8 + srow) * HDd + sswz,
                       Ks + c8 * 512);
            load_lds16(Vbh + (size_t)(c8 * 8 + srow) * Tt + kt + sswz,
                       Vs + c8 * 512);
        }
        __syncthreads();   // vmcnt(0) drain: staging visible

        // QK^T: 4 n-blocks of 16 keys, 2 k-halves of 32 channels
        f32x4 sc[4];
#pragma unroll
        for (int nb = 0; nb < 4; nb++) sc[nb] = z4;
#pragma unroll
        for (int nb = 0; nb < 4; nb++) {
            const bf16* krow = Ks + (nb * 16 + l16) * 64;
            const bf16x8 kf0 = *(const bf16x8*)(krow + ((quad     ^ (l16 & 7)) * 8));
            const bf16x8 kf1 = *(const bf16x8*)(krow + (((4 + quad) ^ (l16 & 7)) * 8));
            sc[nb] = __builtin_amdgcn_mfma_f32_16x16x32_bf16(qf0, kf0, sc[nb], 0, 0, 0);
            sc[nb] = __builtin_amdgcn_mfma_f32_16x16x32_bf16(qf1, kf1, sc[nb], 0, 0, 0);
        }

        // softmax numerator (no max subtraction) + P store (C->A layout)
#pragma unroll
        for (int nb = 0; nb < 4; nb++) {
            const float madd = mb[kt + nb * 16 + l16] ? 0.f : -1e30f;
#pragma unroll
            for (int r = 0; r < 4; r++) {
                const float p = __expf(sc[nb][r] * 0.125f + madd);
                ls[r] += p;
                Psw[(quad * 4 + r) * 72 + nb * 16 + l16] = (bf16)p;
            }
        }

        // O += P @ V : A = P (rows q), B = V^T (rows d), k = t in 2 halves
#pragma unroll
        for (int kh = 0; kh < 2; kh++) {
            const bf16x8 pf = *(const bf16x8*)(Psw + l16 * 72 + kh * 32 + quad * 8);
#pragma unroll
            for (int dblk = 0; dblk < 4; dblk++) {
                const bf16x8 vf = *(const bf16x8*)(Vs + (dblk * 16 + l16) * 64 +
                                                   (((kh * 4 + quad) ^ (l16 & 7)) * 8));
                o[dblk] = __builtin_amdgcn_mfma_f32_16x16x32_bf16(pf, vf, o[dblk], 0, 0, 0);
            }
        }
        __syncthreads();   // all reads done before next stage overwrites
    }

    // row sums: reduce ls across the 16 l16 lanes
#pragma unroll
    for (int off = 1; off <= 8; off <<= 1)
#pragma unroll
        for (int r = 0; r < 4; r++)
            ls[r] += __shfl_xor(ls[r], off, 64);
    float inv[4];
#pragma unroll
    for (int r = 0; r < 4; r++) inv[r] = 1.f / ls[r];

#pragma unroll
    for (int dblk = 0; dblk < 4; dblk++) {
#pragma unroll
        for (int r = 0; r < 4; r++) {
            const int srow_q = q0 + quad * 4 + r;
            const int d = dblk * 16 + l16;
            X[(size_t)(b * Ss + srow_q) * Cc + h * HDd + d] = (bf16)(o[dblk][r] * inv[r]);
        }
    }
}

// ---------------------------------------------------------------------------
extern "C" void kernel_launch(void* const* d_in, const int* in_sizes, int n_in,
                              void* d_out, int out_size, void* d_ws, size_t ws_size,
                              hipStream_t stream)
{
    const float* query = (const float*)d_in[0];
    const float* key   = (const float*)d_in[1];
    const float* value = (const float*)d_in[2];
    const int*   mask  = (const int*)d_in[3];
    const float* Wq = (const float*)d_in[4];
    const float* bq = (const float*)d_in[5];
    const float* Wk = (const float*)d_in[6];
    const float* bk = (const float*)d_in[7];
    const float* Wv = (const float*)d_in[8];
    const float* bv = (const float*)d_in[9];
    const float* Wo = (const float*)d_in[10];
    const float* bo = (const float*)d_in[11];
    float* out = (float*)d_out;

    char* ws = (char*)d_ws;
    const size_t MB = 1024 * 1024;
    bf16* qb  = (bf16*)(ws + 0 * MB);
    bf16* kb  = (bf16*)(ws + 8 * MB);
    bf16* vb  = (bf16*)(ws + 16 * MB);
    bf16* wqb = (bf16*)(ws + 24 * MB);
    bf16* wkb = (bf16*)(ws + 26 * MB);
    bf16* wvb = (bf16*)(ws + 28 * MB);
    bf16* wob = (bf16*)(ws + 30 * MB);
    bf16* Qp  = (bf16*)(ws + 32 * MB);   // (B,H,S,HD) bf16
    bf16* Kpp = (bf16*)(ws + 40 * MB);   // (B,H,T,HD) bf16
    bf16* Vtp = (bf16*)(ws + 48 * MB);   // (B,H,HD,T) bf16
    bf16* Xb  = (bf16*)(ws + 56 * MB);   // attn out (B*S, C) bf16

    cvt8<<<dim3(2048, 7), 256, 0, stream>>>(query, key, value, Wq, Wk, Wv, Wo,
                                            qb, kb, vb, wqb, wkb, wvb, wob);
    gemm_qkv<<<dim3(32, 16, 3), 256, 0, stream>>>(qb, kb, vb, wqb, wkb, wvb,
                                                  bq, bk, bv, Qp, Kpp, Vtp);
    attn<<<dim3(1024), 256, 0, stream>>>(Qp, Kpp, Vtp, mask, Xb);
    gemm_out<<<dim3(64, 16), 256, 0, stream>>>(Xb, wob, bo, mask, out);
}